// Round 13
// baseline (375.455 us; speedup 1.0000x reference)
//
#include <hip/hip_runtime.h>
#include <math.h>

typedef unsigned short u16;
using bf16x8 = __attribute__((ext_vector_type(8))) short;
using f32x4  = __attribute__((ext_vector_type(4))) float;

#define NS      128
#define RPB     4       // rays per block (sequential, head hidden under tail)
#define NBLOCKS (4096 / RPB)
#define NSLICE  19      // 15 (W1) + 4 (W2) unified W slices of 4096 u16
#define OWGT    81920   // u16 offset of fp32 weight table (4096x128 f32, 2 MB)

// LDS pool (u16): X QUAD-buffer = 4 group slots x 8192 u16 = 64 KB.
// Slice s lives at slice-slot (s&7)*4096. h1 overlays slice-slots 0..3;
// h2 overlays slice-slots 4..7 -> epilogue writes never race live readers.
// 6 lgkm-only barriers per ray; next-ray prologue hides under the tail.
#define POOLSZ 32768
#define OH2    16384

// Raw barrier: drain LDS only; global register-prefetches stay in flight.
#define BAR() do { asm volatile("s_waitcnt lgkmcnt(0)" ::: "memory");        \
                   __builtin_amdgcn_s_barrier();                              \
                   asm volatile("" ::: "memory"); } while (0)

#define MF(A,B,C) __builtin_amdgcn_mfma_f32_16x16x32_bf16((A),(B),(C),0,0,0)

__device__ __forceinline__ u16 f2bf(float f) {           // host-prep path only
    unsigned int i = __float_as_uint(f);
    return (u16)((i + 0x7FFFu + ((i >> 16) & 1u)) >> 16);  // RNE
}

// pack two floats to bf16 pair [hi:lo] in one dword (single VALU op, RNE)
__device__ __forceinline__ unsigned pk(float hi, float lo) {
    unsigned r;
    asm("v_cvt_pk_bf16_f32 %0, %1, %2" : "=v"(r) : "v"(lo), "v"(hi));
    return r;
}

// Swizzled A-frag-order offset for a h [128x128] region: XOR (k>>3)&3 into
// the chunk index (readers apply chunk^quad) to spread the epilogue's
// column-wise u16 writes across more banks.
__device__ __forceinline__ int afoff_h(int m, int k) {
    int chunk = ((k >> 5) * 8 + (m >> 4)) * 64 + ((k >> 3) & 3) * 16 + (m & 15);
    chunk ^= (k >> 3) & 3;
    return chunk * 8 + (k & 7);
}

// channel/slot -> original mlp_in k index (reference ordering)
__device__ __forceinline__ int orig_k(int ch, int slot) {
    if (ch < 27) {
        if (slot == 0) return ch;
        if (slot <= 6) return 30 + ch * 6 + (slot - 1);     // sin(app)
        return 192 + ch * 6 + (slot - 7);                    // cos(app)
    } else {
        int c = ch - 27;
        if (slot == 0) return 27 + c;
        if (slot <= 6) return 354 + c * 6 + (slot - 1);      // sin(view)
        return 372 + c * 6 + (slot - 7);                     // cos(view)
    }
}

__device__ __forceinline__ float ldch(const float* ap, const float* vp, int c) {
    return (c < 27) ? ap[c] : vp[c - 27];
}

// build one channel-half of a frag-order X slice at a precomputed dst:
// slots [v, sin f0..5, cos f0..5, 0 x3] as two 16B chunks (dst, dst+128).
__device__ __forceinline__ void build_x(u16* dst, float v) {
    float rev = v * 0.15915494309189535f;
    rev -= floorf(rev);
    float s0 = __builtin_amdgcn_sinf(rev);
    float c0 = __builtin_amdgcn_cosf(rev);
    float s1 = 2.f * s0 * c0, c1 = c0 * c0 - s0 * s0;
    float s2 = 2.f * s1 * c1, c2 = c1 * c1 - s1 * s1;
    float s3 = 2.f * s2 * c2, c3 = c2 * c2 - s2 * s2;
    float s4 = 2.f * s3 * c3, c4 = c3 * c3 - s3 * s3;
    float s5 = 2.f * s4 * c4, c5 = c4 * c4 - s4 * s4;
    uint4 lo, hi;
    lo.x = pk(s0, v);  lo.y = pk(s2, s1);  lo.z = pk(s4, s3);  lo.w = pk(c0, s5);
    hi.x = pk(c2, c1); hi.y = pk(c4, c3);  hi.z = pk(0.f, c5); hi.w = 0u;
    *(uint4*)(dst)       = lo;
    *(uint4*)(dst + 128) = hi;
}

// W1 -> 15 slices, W2 -> 4 slices, W3 -> 4 mini B-frag slices (N padded 16);
// zeroes the output; computes per-ray transmittance weights (one wave/ray,
// identical shuffle-scan math to the in-render scan -> bit-exact).
__global__ __launch_bounds__(256) void prep_kernel(
    const float* __restrict__ W1, const float* __restrict__ W2,
    const float* __restrict__ W3, const float* __restrict__ sigma_g,
    const float* __restrict__ dists_g, u16* __restrict__ ws,
    float* __restrict__ out)
{
    int idx = blockIdx.x * 256 + threadIdx.x;
    if (idx < 12288) out[idx] = 0.f;                 // 4096 rays x 3
    if (idx < 61440) {                               // W1r: [ks15][nt8][lane64][j8]
        int j = idx & 7, lane = (idx >> 3) & 63, nt = (idx >> 9) & 7, ks = idx >> 12;
        int q = lane >> 4, l15 = lane & 15;
        int klocal = q * 8 + j;                      // 0..31
        int ch = ks * 2 + (klocal >> 4);
        int slot = klocal & 15;
        int n = nt * 16 + l15;
        ws[idx] = (slot < 13) ? f2bf(W1[orig_k(ch, slot) * 128 + n]) : (u16)0;
    } else if (idx < 77824) {                        // W2r: [ks4][nt8][lane64][j8]
        int i2 = idx - 61440;
        int j = i2 & 7, lane = (i2 >> 3) & 63, nt = (i2 >> 9) & 7, ks = i2 >> 12;
        int k = ks * 32 + (lane >> 4) * 8 + j;
        int n = nt * 16 + (lane & 15);
        ws[idx] = f2bf(W2[k * 128 + n]);
    } else if (idx < 79872) {                        // W3r: [ks4][lane64][j8], N pad 16
        int i3 = idx - 77824;
        int j = i3 & 7, lane = (i3 >> 3) & 63, ks = i3 >> 9;
        int k = ks * 32 + (lane >> 4) * 8 + j;
        int n = lane & 15;
        ws[idx] = (n < 3) ? f2bf(W3[k * 3 + n]) : (u16)0;
    }
    // ---- weights: wave (idx>>6) owns ray (idx>>6); lane ln handles samples
    // ln and ln+64 (same op sequence as the old two-wave render scan). ----
    {
        int ray = idx >> 6, ln = idx & 63;           // 1024 blocks x 4 waves = 4096
        float* wgt = (float*)(ws + OWGT);
        int base = ray * NS;
        float x0 = sigma_g[base + ln] - 10.f;
        float sp0 = (x0 > 20.f) ? x0 : log1pf(expf(x0));
        float a0 = 1.f - expf(-sp0 * dists_g[base + ln] * 25.f);
        float x1 = sigma_g[base + 64 + ln] - 10.f;
        float sp1 = (x1 > 20.f) ? x1 : log1pf(expf(x1));
        float a1 = 1.f - expf(-sp1 * dists_g[base + 64 + ln] * 25.f);
        if (ln == 63) a1 = 1.f;                      // last sample forced opaque
        float p0 = 1.f - a0 + 1e-10f;
        float p1 = 1.f - a1 + 1e-10f;
        #pragma unroll
        for (int d = 1; d < 64; d <<= 1) {
            float v0 = __shfl_up(p0, d);
            float v1 = __shfl_up(p1, d);
            if (ln >= d) { p0 *= v0; p1 *= v1; }
        }
        float S0 = __shfl(p0, 63);                   // first-half total
        float q0 = __shfl_up(p0, 1);
        float q1 = __shfl_up(p1, 1);
        wgt[base + ln]      = a0 * ((ln == 0) ? 1.f : q0);
        wgt[base + 64 + ln] = a1 * ((ln == 0) ? 1.f : q1) * S0;
    }
}

// Load one slice's 2 B-frags (wave's 32-col strip) into named registers.
#define LOADB2(N0, N1, s)                                                     \
    if ((s) < NSLICE) {                                                       \
        const u16* wp = wp0 + (s) * 4096;                                     \
        N0 = *(const bf16x8*)(wp);                                            \
        N1 = *(const bf16x8*)(wp + 512);                                      \
    }

// One X-sourced K-slice: 4 A ds_reads (64-row strip, split 2+2) + 8 MFMA.
// Loads slice s+2's B-frags (3-pair rotation P,Q,R).
#define BODYX(s, C0,C1, N0,N1)                                                \
  {                                                                           \
    LOADB2(N0, N1, (s)+2);                                                    \
    const u16* ab = pool + ((s)&7)*4096 + (wm*256 + lane)*8;                  \
    bf16x8 a0 = *(const bf16x8*)(ab);                                         \
    bf16x8 a1 = *(const bf16x8*)(ab + 512);                                   \
    __builtin_amdgcn_s_setprio(1);                                            \
    acc[0][0]=MF(a0,C0,acc[0][0]); acc[0][1]=MF(a0,C1,acc[0][1]);             \
    acc[1][0]=MF(a1,C0,acc[1][0]); acc[1][1]=MF(a1,C1,acc[1][1]);             \
    a0 = *(const bf16x8*)(ab + 1024);                                         \
    a1 = *(const bf16x8*)(ab + 1536);                                         \
    acc[2][0]=MF(a0,C0,acc[2][0]); acc[2][1]=MF(a0,C1,acc[2][1]);             \
    acc[3][0]=MF(a1,C0,acc[3][0]); acc[3][1]=MF(a1,C1,acc[3][1]);             \
    __builtin_amdgcn_s_setprio(0);                                            \
  }

// First slice: C-in = 0 folded into the MFMA (no acc zero-init pass).
#define BODYX0(s, C0,C1, N0,N1)                                               \
  {                                                                           \
    LOADB2(N0, N1, (s)+2);                                                    \
    const u16* ab = pool + ((s)&7)*4096 + (wm*256 + lane)*8;                  \
    bf16x8 a0 = *(const bf16x8*)(ab);                                         \
    bf16x8 a1 = *(const bf16x8*)(ab + 512);                                   \
    __builtin_amdgcn_s_setprio(1);                                            \
    acc[0][0]=MF(a0,C0,vzero); acc[0][1]=MF(a0,C1,vzero);                     \
    acc[1][0]=MF(a1,C0,vzero); acc[1][1]=MF(a1,C1,vzero);                     \
    a0 = *(const bf16x8*)(ab + 1024);                                         \
    a1 = *(const bf16x8*)(ab + 1536);                                         \
    acc[2][0]=MF(a0,C0,vzero); acc[2][1]=MF(a0,C1,vzero);                     \
    acc[3][0]=MF(a1,C0,vzero); acc[3][1]=MF(a1,C1,vzero);                     \
    __builtin_amdgcn_s_setprio(0);                                            \
  }

// One h-sourced K-slice (GEMM2): A from swizzled h1 chunks (slice-slots 0..3).
#define BODYH(s, C0,C1, N0,N1)                                                \
  {                                                                           \
    LOADB2(N0, N1, (s)+2);                                                    \
    int cb = ((((s)-15)*512) + wm*256 + lane) ^ quad;                         \
    bf16x8 a0 = *(const bf16x8*)(pool + cb*8);                                \
    bf16x8 a1 = *(const bf16x8*)(pool + (cb+64)*8);                           \
    __builtin_amdgcn_s_setprio(1);                                            \
    acc[0][0]=MF(a0,C0,acc[0][0]); acc[0][1]=MF(a0,C1,acc[0][1]);             \
    acc[1][0]=MF(a1,C0,acc[1][0]); acc[1][1]=MF(a1,C1,acc[1][1]);             \
    a0 = *(const bf16x8*)(pool + (cb+128)*8);                                 \
    a1 = *(const bf16x8*)(pool + (cb+192)*8);                                 \
    acc[2][0]=MF(a0,C0,acc[2][0]); acc[2][1]=MF(a0,C1,acc[2][1]);             \
    acc[3][0]=MF(a1,C0,acc[3][0]); acc[3][1]=MF(a1,C1,acc[3][1]);             \
    __builtin_amdgcn_s_setprio(0);                                            \
  }

// First GEMM2 slice: C-in = 0 folded in (no acc reset pass after epilogue 1).
#define BODYH0(s, C0,C1, N0,N1)                                               \
  {                                                                           \
    LOADB2(N0, N1, (s)+2);                                                    \
    int cb = ((((s)-15)*512) + wm*256 + lane) ^ quad;                         \
    bf16x8 a0 = *(const bf16x8*)(pool + cb*8);                                \
    bf16x8 a1 = *(const bf16x8*)(pool + (cb+64)*8);                           \
    __builtin_amdgcn_s_setprio(1);                                            \
    acc[0][0]=MF(a0,C0,vzero); acc[0][1]=MF(a0,C1,vzero);                     \
    acc[1][0]=MF(a1,C0,vzero); acc[1][1]=MF(a1,C1,vzero);                     \
    a0 = *(const bf16x8*)(pool + (cb+128)*8);                                 \
    a1 = *(const bf16x8*)(pool + (cb+192)*8);                                 \
    acc[2][0]=MF(a0,C0,vzero); acc[2][1]=MF(a0,C1,vzero);                     \
    acc[3][0]=MF(a1,C0,vzero); acc[3][1]=MF(a1,C1,vzero);                     \
    __builtin_amdgcn_s_setprio(0);                                            \
  }

// End of 2-group phase p: build groups 2p+2, 2p+3 into their slots, roll the
// 4-deep input prefetch (load groups 2p+6, 2p+7), single barrier.
#define GENDQ(p)                                                              \
  {                                                                           \
    if (8*(p)+8  + cl < 30)                                                   \
        build_x(pool + ((2*(p)+2)&3)*8192 + (cl>>1)*4096 + bxoff, pv_a);      \
    if (8*(p)+12 + cl < 30)                                                   \
        build_x(pool + ((2*(p)+3)&3)*8192 + (cl>>1)*4096 + bxoff, pv_b);      \
    pv_a = pv_c; pv_b = pv_d;                                                 \
    if (8*(p)+24 + cl < 30) pv_c = ldch(ap, vp, 8*(p)+24 + cl);               \
    if (8*(p)+28 + cl < 30) pv_d = ldch(ap, vp, 8*(p)+28 + cl);               \
    BAR();                                                                    \
  }

// Vectorized epilogue store: packed add/max + paired bf16 cvt, 4 u16 writes.
#define EPI4(OFS, ACC, BB, rwb, col)                                          \
  { f32x4 t_ = ACC + BB;                                                      \
    t_ = __builtin_elementwise_max(t_, vzero);                                \
    unsigned w01_ = pk(t_[1], t_[0]);                                         \
    unsigned w23_ = pk(t_[3], t_[2]);                                         \
    pool[(OFS) + afoff_h((rwb) + 0, col)] = (u16)w01_;                        \
    pool[(OFS) + afoff_h((rwb) + 1, col)] = (u16)(w01_ >> 16);                \
    pool[(OFS) + afoff_h((rwb) + 2, col)] = (u16)w23_;                        \
    pool[(OFS) + afoff_h((rwb) + 3, col)] = (u16)(w23_ >> 16); }

// 8 waves: wave (wm = wave>>2, wn = wave&3) owns a 64x32 output tile
// (A-amp 4 via LDS, B-amp 2 via L1/L2 registers). RPB sequential rays per
// block; each next-ray prologue (input loads + builds + B reloads) hides
// under the previous ray's layer-3 tail -- slots 0..3 (builds) are disjoint
// from slots 4..7 (layer-3 reads), and the ray-boundary BAR doubles as the
// old prologue barrier.
__global__ __launch_bounds__(512, 4) void render_kernel(
    const float* __restrict__ app_g,   const float* __restrict__ view_g,
    const float* __restrict__ b1_g,    const float* __restrict__ b2_g,
    const float* __restrict__ b3_g,    const u16* __restrict__ ws,
    float* __restrict__ out_g)
{
    __shared__ __align__(16) u16 pool[POOLSZ];

    const int tid  = threadIdx.x;
    const int lane = tid & 63;
    const int wave = tid >> 6;       // 0..7
    const int l15  = lane & 15;
    const int quad = lane >> 4;
    const int wm   = wave >> 2;      // row half (64 rows)
    const int wn   = wave & 3;       // col quarter (32 cols)

    const int r0  = blockIdx.x * RPB;
    const int rowl = tid & 127;      // X-build row (all 512 threads build)
    const int cl   = tid >> 7;       // X-build channel-local 0..3 (2 slices)
    const float* ap = app_g  + (r0 * NS + rowl) * 27;
    const float* vp = view_g + (r0 * NS + rowl) * 3;
    // hoisted per-thread build offset within a slice
    const int bxoff = (rowl >> 4) * 512 + (((cl & 1) * 32) + (rowl & 15)) * 8;

    // issue B loads for slices 0,1 ASAP (3-pair rotation P,Q,R)
    const u16* wp0 = ws + (wn * 128 + lane) * 8;
    bf16x8 bP0, bP1, bQ0, bQ1, bR0, bR1;
    LOADB2(bP0, bP1, 0);
    LOADB2(bQ0, bQ1, 1);

    // rolling input prefetch (4 resident: groups g..g+3's channel values)
    float pv_a = ldch(ap, vp, cl);           // g0
    float pv_b = ldch(ap, vp, 4 + cl);       // g1
    float pv_c = ldch(ap, vp, 8 + cl);       // g2
    float pv_d = ldch(ap, vp, 12 + cl);      // g3

    // ---- ray-0 prologue: build X groups 0,1 (slices 0..3) into slots 0,1 ----
    build_x(pool +        (cl >> 1) * 4096 + bxoff, pv_a);
    build_x(pool + 8192 + (cl >> 1) * 4096 + bxoff, pv_b);
    pv_a = pv_c; pv_b = pv_d;
    pv_c = ldch(ap, vp, 16 + cl);            // g4
    pv_d = ldch(ap, vp, 20 + cl);            // g5
    BAR();

    const f32x4 vzero = {0.f, 0.f, 0.f, 0.f};
    const u16* w3r = ws + 77824;
    const float b3v = (l15 < 3) ? b3_g[l15] : 0.f;
    f32x4 acc[4][2];

    #pragma unroll 1
    for (int ri = 0; ri < RPB; ++ri) {
        // ---- GEMM1: slices 0..14, 4-slice phases (pair s%3: 0=P 1=Q 2=R) ----
        BODYX0(0, bP0,bP1, bR0,bR1);              // C=0 folded
        BODYX(1,  bQ0,bQ1, bP0,bP1);
        BODYX(2,  bR0,bR1, bQ0,bQ1);
        BODYX(3,  bP0,bP1, bR0,bR1);  GENDQ(0);   // builds g2,g3 (slices 4..7)
        BODYX(4,  bQ0,bQ1, bP0,bP1);
        BODYX(5,  bR0,bR1, bQ0,bQ1);
        BODYX(6,  bP0,bP1, bR0,bR1);
        BODYX(7,  bQ0,bQ1, bP0,bP1);  GENDQ(1);   // builds g4,g5 (slices 8..11)
        BODYX(8,  bR0,bR1, bQ0,bQ1);
        BODYX(9,  bP0,bP1, bR0,bR1);
        BODYX(10, bQ0,bQ1, bP0,bP1);
        BODYX(11, bR0,bR1, bQ0,bQ1);  GENDQ(2);   // builds g6,g7 (slices 12..14)

        // next-ray input prefetch: pv regs are dead after GENDQ(2); the HBM
        // latency hides under slices 12..14 + GEMM2 (~10 slices of work)
        if (ri + 1 < RPB) {
            ap += NS * 27; vp += NS * 3;
            pv_a = ldch(ap, vp, cl);
            pv_b = ldch(ap, vp, 4 + cl);
            pv_c = ldch(ap, vp, 8 + cl);
            pv_d = ldch(ap, vp, 12 + cl);
        }
        // b1 issued here so its latency hides under the last GEMM1 phase
        const float b1r0 = b1_g[wn * 32 + l15];
        const float b1r1 = b1_g[wn * 32 + 16 + l15];
        BODYX(12, bP0,bP1, bR0,bR1);
        BODYX(13, bQ0,bQ1, bP0,bP1);              // loads slice 15 -> P
        BODYX(14, bR0,bR1, bQ0,bQ1);              // loads slice 16 -> Q

        // ---- epilogue 1 (NO pre-barrier): h1 -> slots 0..3; concurrent
        // slice-12..14 reads live in slots 4..6 (disjoint). ----
        {
            const f32x4 bb0 = {b1r0, b1r0, b1r0, b1r0};
            const f32x4 bb1 = {b1r1, b1r1, b1r1, b1r1};
            #pragma unroll
            for (int mt = 0; mt < 4; ++mt) {
                int rwb = wm * 64 + mt * 16 + quad * 4;
                EPI4(0, acc[mt][0], bb0, rwb, wn * 32 + l15);
                EPI4(0, acc[mt][1], bb1, rwb, wn * 32 + 16 + l15);
            }
        }
        BAR();   // h1 visible to all waves AND slot-4..6 reads drained

        const float b2r0 = b2_g[wn * 32 + l15];
        const float b2r1 = b2_g[wn * 32 + 16 + l15];

        // ---- GEMM2: slices 15..18 (h1 @ W2), barrier-free run ----
        BODYH0(15, bP0,bP1, bR0,bR1);             // C=0 folded; loads 17 -> R
        BODYH(16, bQ0,bQ1, bP0,bP1);              // loads slice 18 -> P
        BODYH(17, bR0,bR1, bQ0,bQ1);
        BODYH(18, bP0,bP1, bR0,bR1);

        // ---- epilogue 2 (NO pre-barrier): h2 -> slots 4..7; concurrent
        // GEMM2 reads live in slots 0..3 (disjoint). ----
        {
            const f32x4 bb0 = {b2r0, b2r0, b2r0, b2r0};
            const f32x4 bb1 = {b2r1, b2r1, b2r1, b2r1};
            #pragma unroll
            for (int mt = 0; mt < 4; ++mt) {
                int rwb = wm * 64 + mt * 16 + quad * 4;
                EPI4(OH2, acc[mt][0], bb0, rwb, wn * 32 + l15);
                EPI4(OH2, acc[mt][1], bb1, rwb, wn * 32 + 16 + l15);
            }
        }
        BAR();   // h2 visible; all h1 (slot 0..3) reads drained

        // ---- tail: layer3 (reads slots 4..7) ∥ next-ray prologue (writes
        // slots 0..3 -- disjoint; prior readers drained at the BAR above) ----
        const float4 w4 = *(const float4*)((const float*)(ws + OWGT)
                          + (r0 + ri) * NS + wave * 16 + quad * 4);
        f32x4 acc3 = vzero;
        #pragma unroll
        for (int ks = 0; ks < 4; ++ks) {
            bf16x8 w3f = *(const bf16x8*)(w3r + (ks * 64 + lane) * 8);
            int c = ((ks * 8 + wave) * 64 + lane) ^ quad;
            bf16x8 a3 = *(const bf16x8*)(pool + OH2 + c * 8);
            acc3 = MF(a3, w3f, acc3);
        }
        if (ri + 1 < RPB) {
            LOADB2(bP0, bP1, 0);                  // next-ray B reload (L1-hot)
            LOADB2(bQ0, bQ1, 1);
            build_x(pool +        (cl >> 1) * 4096 + bxoff, pv_a);
            build_x(pool + 8192 + (cl >> 1) * 4096 + bxoff, pv_b);
            pv_a = pv_c; pv_b = pv_d;
            pv_c = ldch(ap, vp, 16 + cl);         // g4
            pv_d = ldch(ap, vp, 20 + cl);         // g5
        }
        float v = 0.f;
        if (l15 < 3) {
            v  = w4.x / (1.f + expf(-(acc3[0] + b3v)));
            v += w4.y / (1.f + expf(-(acc3[1] + b3v)));
            v += w4.z / (1.f + expf(-(acc3[2] + b3v)));
            v += w4.w / (1.f + expf(-(acc3[3] + b3v)));
        }
        v += __shfl_xor(v, 16);      // sum the 4 quads (rows) of this wave
        v += __shfl_xor(v, 32);
        if (lane < 3)                // out zeroed by prep; 8 wave-partials/color
            atomicAdd(&out_g[(r0 + ri) * 3 + lane], v);

        if (ri + 1 < RPB) BAR();     // ray boundary == next ray's prologue BAR
    }
}

extern "C" void kernel_launch(void* const* d_in, const int* in_sizes, int n_in,
                              void* d_out, int out_size, void* d_ws, size_t ws_size,
                              hipStream_t stream) {
    (void)in_sizes; (void)n_in; (void)out_size; (void)ws_size;
    const float* sigma = (const float*)d_in[0];
    const float* app   = (const float*)d_in[1];
    const float* view  = (const float*)d_in[2];
    const float* dists = (const float*)d_in[3];
    const float* W1    = (const float*)d_in[4];
    const float* b1    = (const float*)d_in[5];
    const float* W2    = (const float*)d_in[6];
    const float* b2    = (const float*)d_in[7];
    const float* W3    = (const float*)d_in[8];
    const float* b3    = (const float*)d_in[9];
    float* out = (float*)d_out;

    u16* ws = (u16*)d_ws;   // 159744 B frag tables + 2 MB fp32 weights @ OWGT

    prep_kernel<<<1024, 256, 0, stream>>>(W1, W2, W3, sigma, dists, ws, out);
    render_kernel<<<NBLOCKS, 512, 0, stream>>>(app, view, b1, b2, b3, ws, out);
}

// Round 14
// 234.967 us; speedup vs baseline: 1.5979x; 1.5979x over previous
//
#include <hip/hip_runtime.h>
#include <math.h>

typedef unsigned short u16;
using bf16x8 = __attribute__((ext_vector_type(8))) short;
using f32x4  = __attribute__((ext_vector_type(4))) float;

#define NS      128
#define RPB     2       // rays per block, straight-line duplicated (NO loop --
                        // a back-edge makes the allocator spill, round 13)
#define NBLOCKS (4096 / RPB)
#define NSLICE  19      // 15 (W1) + 4 (W2) unified W slices of 4096 u16
#define OWGT    81920   // u16 offset of fp32 weight table (4096x128 f32, 2 MB)

// LDS pool (u16): X QUAD-buffer = 4 group slots x 8192 u16 = 64 KB.
// Slice s lives at slice-slot (s&7)*4096. h1 overlays slice-slots 0..3;
// h2 overlays slice-slots 4..7 -> epilogue writes never race live readers.
// 6 lgkm-only barriers per ray; ray-1 prologue hides under ray-0's tail.
#define POOLSZ 32768
#define OH2    16384

// Raw barrier: drain LDS only; global register-prefetches stay in flight.
#define BAR() do { asm volatile("s_waitcnt lgkmcnt(0)" ::: "memory");        \
                   __builtin_amdgcn_s_barrier();                              \
                   asm volatile("" ::: "memory"); } while (0)

#define MF(A,B,C) __builtin_amdgcn_mfma_f32_16x16x32_bf16((A),(B),(C),0,0,0)

__device__ __forceinline__ u16 f2bf(float f) {           // host-prep path only
    unsigned int i = __float_as_uint(f);
    return (u16)((i + 0x7FFFu + ((i >> 16) & 1u)) >> 16);  // RNE
}

// pack two floats to bf16 pair [hi:lo] in one dword (single VALU op, RNE)
__device__ __forceinline__ unsigned pk(float hi, float lo) {
    unsigned r;
    asm("v_cvt_pk_bf16_f32 %0, %1, %2" : "=v"(r) : "v"(lo), "v"(hi));
    return r;
}

// Swizzled A-frag-order offset for a h [128x128] region: XOR (k>>3)&3 into
// the chunk index (readers apply chunk^quad) to spread the epilogue's
// column-wise u16 writes across more banks.
__device__ __forceinline__ int afoff_h(int m, int k) {
    int chunk = ((k >> 5) * 8 + (m >> 4)) * 64 + ((k >> 3) & 3) * 16 + (m & 15);
    chunk ^= (k >> 3) & 3;
    return chunk * 8 + (k & 7);
}

// channel/slot -> original mlp_in k index (reference ordering)
__device__ __forceinline__ int orig_k(int ch, int slot) {
    if (ch < 27) {
        if (slot == 0) return ch;
        if (slot <= 6) return 30 + ch * 6 + (slot - 1);     // sin(app)
        return 192 + ch * 6 + (slot - 7);                    // cos(app)
    } else {
        int c = ch - 27;
        if (slot == 0) return 27 + c;
        if (slot <= 6) return 354 + c * 6 + (slot - 1);      // sin(view)
        return 372 + c * 6 + (slot - 7);                     // cos(view)
    }
}

__device__ __forceinline__ float ldch(const float* ap, const float* vp, int c) {
    return (c < 27) ? ap[c] : vp[c - 27];
}

// build one channel-half of a frag-order X slice at a precomputed dst:
// slots [v, sin f0..5, cos f0..5, 0 x3] as two 16B chunks (dst, dst+128).
__device__ __forceinline__ void build_x(u16* dst, float v) {
    float rev = v * 0.15915494309189535f;
    rev -= floorf(rev);
    float s0 = __builtin_amdgcn_sinf(rev);
    float c0 = __builtin_amdgcn_cosf(rev);
    float s1 = 2.f * s0 * c0, c1 = c0 * c0 - s0 * s0;
    float s2 = 2.f * s1 * c1, c2 = c1 * c1 - s1 * s1;
    float s3 = 2.f * s2 * c2, c3 = c2 * c2 - s2 * s2;
    float s4 = 2.f * s3 * c3, c4 = c3 * c3 - s3 * s3;
    float s5 = 2.f * s4 * c4, c5 = c4 * c4 - s4 * s4;
    uint4 lo, hi;
    lo.x = pk(s0, v);  lo.y = pk(s2, s1);  lo.z = pk(s4, s3);  lo.w = pk(c0, s5);
    hi.x = pk(c2, c1); hi.y = pk(c4, c3);  hi.z = pk(0.f, c5); hi.w = 0u;
    *(uint4*)(dst)       = lo;
    *(uint4*)(dst + 128) = hi;
}

// W1 -> 15 slices, W2 -> 4 slices, W3 -> 4 mini B-frag slices (N padded 16);
// zeroes the output; computes per-ray transmittance weights (one wave/ray,
// identical shuffle-scan math to the in-render scan -> bit-exact).
__global__ __launch_bounds__(256) void prep_kernel(
    const float* __restrict__ W1, const float* __restrict__ W2,
    const float* __restrict__ W3, const float* __restrict__ sigma_g,
    const float* __restrict__ dists_g, u16* __restrict__ ws,
    float* __restrict__ out)
{
    int idx = blockIdx.x * 256 + threadIdx.x;
    if (idx < 12288) out[idx] = 0.f;                 // 4096 rays x 3
    if (idx < 61440) {                               // W1r: [ks15][nt8][lane64][j8]
        int j = idx & 7, lane = (idx >> 3) & 63, nt = (idx >> 9) & 7, ks = idx >> 12;
        int q = lane >> 4, l15 = lane & 15;
        int klocal = q * 8 + j;                      // 0..31
        int ch = ks * 2 + (klocal >> 4);
        int slot = klocal & 15;
        int n = nt * 16 + l15;
        ws[idx] = (slot < 13) ? f2bf(W1[orig_k(ch, slot) * 128 + n]) : (u16)0;
    } else if (idx < 77824) {                        // W2r: [ks4][nt8][lane64][j8]
        int i2 = idx - 61440;
        int j = i2 & 7, lane = (i2 >> 3) & 63, nt = (i2 >> 9) & 7, ks = i2 >> 12;
        int k = ks * 32 + (lane >> 4) * 8 + j;
        int n = nt * 16 + (lane & 15);
        ws[idx] = f2bf(W2[k * 128 + n]);
    } else if (idx < 79872) {                        // W3r: [ks4][lane64][j8], N pad 16
        int i3 = idx - 77824;
        int j = i3 & 7, lane = (i3 >> 3) & 63, ks = i3 >> 9;
        int k = ks * 32 + (lane >> 4) * 8 + j;
        int n = lane & 15;
        ws[idx] = (n < 3) ? f2bf(W3[k * 3 + n]) : (u16)0;
    }
    // ---- weights: wave (idx>>6) owns ray (idx>>6); lane ln handles samples
    // ln and ln+64 (same op sequence as the old two-wave render scan). ----
    {
        int ray = idx >> 6, ln = idx & 63;           // 1024 blocks x 4 waves = 4096
        float* wgt = (float*)(ws + OWGT);
        int base = ray * NS;
        float x0 = sigma_g[base + ln] - 10.f;
        float sp0 = (x0 > 20.f) ? x0 : log1pf(expf(x0));
        float a0 = 1.f - expf(-sp0 * dists_g[base + ln] * 25.f);
        float x1 = sigma_g[base + 64 + ln] - 10.f;
        float sp1 = (x1 > 20.f) ? x1 : log1pf(expf(x1));
        float a1 = 1.f - expf(-sp1 * dists_g[base + 64 + ln] * 25.f);
        if (ln == 63) a1 = 1.f;                      // last sample forced opaque
        float p0 = 1.f - a0 + 1e-10f;
        float p1 = 1.f - a1 + 1e-10f;
        #pragma unroll
        for (int d = 1; d < 64; d <<= 1) {
            float v0 = __shfl_up(p0, d);
            float v1 = __shfl_up(p1, d);
            if (ln >= d) { p0 *= v0; p1 *= v1; }
        }
        float S0 = __shfl(p0, 63);                   // first-half total
        float q0 = __shfl_up(p0, 1);
        float q1 = __shfl_up(p1, 1);
        wgt[base + ln]      = a0 * ((ln == 0) ? 1.f : q0);
        wgt[base + 64 + ln] = a1 * ((ln == 0) ? 1.f : q1) * S0;
    }
}

// Load one slice's 2 B-frags (wave's 32-col strip) into named registers.
#define LOADB2(N0, N1, s)                                                     \
    if ((s) < NSLICE) {                                                       \
        const u16* wp = wp0 + (s) * 4096;                                     \
        N0 = *(const bf16x8*)(wp);                                            \
        N1 = *(const bf16x8*)(wp + 512);                                      \
    }

// One X-sourced K-slice: 4 A ds_reads (64-row strip, split 2+2) + 8 MFMA.
// Loads slice s+2's B-frags (3-pair rotation P,Q,R).
#define BODYX(s, C0,C1, N0,N1)                                                \
  {                                                                           \
    LOADB2(N0, N1, (s)+2);                                                    \
    const u16* ab = pool + ((s)&7)*4096 + (wm*256 + lane)*8;                  \
    bf16x8 a0 = *(const bf16x8*)(ab);                                         \
    bf16x8 a1 = *(const bf16x8*)(ab + 512);                                   \
    __builtin_amdgcn_s_setprio(1);                                            \
    acc[0][0]=MF(a0,C0,acc[0][0]); acc[0][1]=MF(a0,C1,acc[0][1]);             \
    acc[1][0]=MF(a1,C0,acc[1][0]); acc[1][1]=MF(a1,C1,acc[1][1]);             \
    a0 = *(const bf16x8*)(ab + 1024);                                         \
    a1 = *(const bf16x8*)(ab + 1536);                                         \
    acc[2][0]=MF(a0,C0,acc[2][0]); acc[2][1]=MF(a0,C1,acc[2][1]);             \
    acc[3][0]=MF(a1,C0,acc[3][0]); acc[3][1]=MF(a1,C1,acc[3][1]);             \
    __builtin_amdgcn_s_setprio(0);                                            \
  }

// First slice: C-in = 0 folded into the MFMA (no acc zero-init pass).
#define BODYX0(s, C0,C1, N0,N1)                                               \
  {                                                                           \
    LOADB2(N0, N1, (s)+2);                                                    \
    const u16* ab = pool + ((s)&7)*4096 + (wm*256 + lane)*8;                  \
    bf16x8 a0 = *(const bf16x8*)(ab);                                         \
    bf16x8 a1 = *(const bf16x8*)(ab + 512);                                   \
    __builtin_amdgcn_s_setprio(1);                                            \
    acc[0][0]=MF(a0,C0,vzero); acc[0][1]=MF(a0,C1,vzero);                     \
    acc[1][0]=MF(a1,C0,vzero); acc[1][1]=MF(a1,C1,vzero);                     \
    a0 = *(const bf16x8*)(ab + 1024);                                         \
    a1 = *(const bf16x8*)(ab + 1536);                                         \
    acc[2][0]=MF(a0,C0,vzero); acc[2][1]=MF(a0,C1,vzero);                     \
    acc[3][0]=MF(a1,C0,vzero); acc[3][1]=MF(a1,C1,vzero);                     \
    __builtin_amdgcn_s_setprio(0);                                            \
  }

// One h-sourced K-slice (GEMM2): A from swizzled h1 chunks (slice-slots 0..3).
#define BODYH(s, C0,C1, N0,N1)                                                \
  {                                                                           \
    LOADB2(N0, N1, (s)+2);                                                    \
    int cb = ((((s)-15)*512) + wm*256 + lane) ^ quad;                         \
    bf16x8 a0 = *(const bf16x8*)(pool + cb*8);                                \
    bf16x8 a1 = *(const bf16x8*)(pool + (cb+64)*8);                           \
    __builtin_amdgcn_s_setprio(1);                                            \
    acc[0][0]=MF(a0,C0,acc[0][0]); acc[0][1]=MF(a0,C1,acc[0][1]);             \
    acc[1][0]=MF(a1,C0,acc[1][0]); acc[1][1]=MF(a1,C1,acc[1][1]);             \
    a0 = *(const bf16x8*)(pool + (cb+128)*8);                                 \
    a1 = *(const bf16x8*)(pool + (cb+192)*8);                                 \
    acc[2][0]=MF(a0,C0,acc[2][0]); acc[2][1]=MF(a0,C1,acc[2][1]);             \
    acc[3][0]=MF(a1,C0,acc[3][0]); acc[3][1]=MF(a1,C1,acc[3][1]);             \
    __builtin_amdgcn_s_setprio(0);                                            \
  }

// First GEMM2 slice: C-in = 0 folded in (no acc reset pass after epilogue 1).
#define BODYH0(s, C0,C1, N0,N1)                                               \
  {                                                                           \
    LOADB2(N0, N1, (s)+2);                                                    \
    int cb = ((((s)-15)*512) + wm*256 + lane) ^ quad;                         \
    bf16x8 a0 = *(const bf16x8*)(pool + cb*8);                                \
    bf16x8 a1 = *(const bf16x8*)(pool + (cb+64)*8);                           \
    __builtin_amdgcn_s_setprio(1);                                            \
    acc[0][0]=MF(a0,C0,vzero); acc[0][1]=MF(a0,C1,vzero);                     \
    acc[1][0]=MF(a1,C0,vzero); acc[1][1]=MF(a1,C1,vzero);                     \
    a0 = *(const bf16x8*)(pool + (cb+128)*8);                                 \
    a1 = *(const bf16x8*)(pool + (cb+192)*8);                                 \
    acc[2][0]=MF(a0,C0,vzero); acc[2][1]=MF(a0,C1,vzero);                     \
    acc[3][0]=MF(a1,C0,vzero); acc[3][1]=MF(a1,C1,vzero);                     \
    __builtin_amdgcn_s_setprio(0);                                            \
  }

// End of 2-group phase p: build groups 2p+2, 2p+3 into their slots, roll the
// 4-deep input prefetch (load groups 2p+6, 2p+7), single barrier.
#define GENDQ(p)                                                              \
  {                                                                           \
    if (8*(p)+8  + cl < 30)                                                   \
        build_x(pool + ((2*(p)+2)&3)*8192 + (cl>>1)*4096 + bxoff, pv_a);      \
    if (8*(p)+12 + cl < 30)                                                   \
        build_x(pool + ((2*(p)+3)&3)*8192 + (cl>>1)*4096 + bxoff, pv_b);      \
    pv_a = pv_c; pv_b = pv_d;                                                 \
    if (8*(p)+24 + cl < 30) pv_c = ldch(ap, vp, 8*(p)+24 + cl);               \
    if (8*(p)+28 + cl < 30) pv_d = ldch(ap, vp, 8*(p)+28 + cl);               \
    BAR();                                                                    \
  }

// Vectorized epilogue store: packed add/max + paired bf16 cvt, 4 u16 writes.
#define EPI4(OFS, ACC, BB, rwb, col)                                          \
  { f32x4 t_ = ACC + BB;                                                      \
    t_ = __builtin_elementwise_max(t_, vzero);                                \
    unsigned w01_ = pk(t_[1], t_[0]);                                         \
    unsigned w23_ = pk(t_[3], t_[2]);                                         \
    pool[(OFS) + afoff_h((rwb) + 0, col)] = (u16)w01_;                        \
    pool[(OFS) + afoff_h((rwb) + 1, col)] = (u16)(w01_ >> 16);                \
    pool[(OFS) + afoff_h((rwb) + 2, col)] = (u16)w23_;                        \
    pool[(OFS) + afoff_h((rwb) + 3, col)] = (u16)(w23_ >> 16); }

// One full ray: GEMM1 + ep1 + GEMM2 + ep2 + tail. PREF=1 interleaves the
// NEXT ray's prologue (input loads after GENDQ(2); builds + B reloads under
// the layer-3 tail -- slots 0..3 are drained by the ep2 barrier).
#define RAY(RI, PREF)                                                         \
  {                                                                           \
    BODYX0(0, bP0,bP1, bR0,bR1);              /* C=0 folded */                \
    BODYX(1,  bQ0,bQ1, bP0,bP1);                                              \
    BODYX(2,  bR0,bR1, bQ0,bQ1);                                              \
    BODYX(3,  bP0,bP1, bR0,bR1);  GENDQ(0);   /* builds slices 4..7 */        \
    BODYX(4,  bQ0,bQ1, bP0,bP1);                                              \
    BODYX(5,  bR0,bR1, bQ0,bQ1);                                              \
    BODYX(6,  bP0,bP1, bR0,bR1);                                              \
    BODYX(7,  bQ0,bQ1, bP0,bP1);  GENDQ(1);   /* builds slices 8..11 */       \
    BODYX(8,  bR0,bR1, bQ0,bQ1);                                              \
    BODYX(9,  bP0,bP1, bR0,bR1);                                              \
    BODYX(10, bQ0,bQ1, bP0,bP1);                                              \
    BODYX(11, bR0,bR1, bQ0,bQ1);  GENDQ(2);   /* builds slices 12..14 */      \
    if (PREF) {  /* next-ray inputs: HBM latency hides under slices 12..18 */ \
        ap += NS * 27; vp += NS * 3;                                          \
        pv_a = ldch(ap, vp, cl);                                              \
        pv_b = ldch(ap, vp, 4 + cl);                                          \
        pv_c = ldch(ap, vp, 8 + cl);                                          \
        pv_d = ldch(ap, vp, 12 + cl);                                         \
    }                                                                         \
    const float b1r0 = b1_g[wn * 32 + l15];                                   \
    const float b1r1 = b1_g[wn * 32 + 16 + l15];                              \
    BODYX(12, bP0,bP1, bR0,bR1);                                              \
    BODYX(13, bQ0,bQ1, bP0,bP1);              /* loads slice 15 -> P */       \
    BODYX(14, bR0,bR1, bQ0,bQ1);              /* loads slice 16 -> Q */       \
    /* ep1 (no pre-barrier): h1 -> slots 0..3; live reads in slots 4..6 */    \
    {                                                                         \
        const f32x4 bb0 = {b1r0, b1r0, b1r0, b1r0};                           \
        const f32x4 bb1 = {b1r1, b1r1, b1r1, b1r1};                           \
        _Pragma("unroll")                                                     \
        for (int mt = 0; mt < 4; ++mt) {                                      \
            int rwb = wm * 64 + mt * 16 + quad * 4;                           \
            EPI4(0, acc[mt][0], bb0, rwb, wn * 32 + l15);                     \
            EPI4(0, acc[mt][1], bb1, rwb, wn * 32 + 16 + l15);                \
        }                                                                     \
    }                                                                         \
    BAR();   /* h1 visible; slot-4..6 reads drained */                        \
    const float b2r0 = b2_g[wn * 32 + l15];                                   \
    const float b2r1 = b2_g[wn * 32 + 16 + l15];                              \
    BODYH0(15, bP0,bP1, bR0,bR1);             /* C=0 folded; loads 17 -> R */ \
    BODYH(16, bQ0,bQ1, bP0,bP1);              /* loads slice 18 -> P */       \
    BODYH(17, bR0,bR1, bQ0,bQ1);                                              \
    BODYH(18, bP0,bP1, bR0,bR1);                                              \
    /* ep2 (no pre-barrier): h2 -> slots 4..7; live reads in slots 0..3 */    \
    {                                                                         \
        const f32x4 bb0 = {b2r0, b2r0, b2r0, b2r0};                           \
        const f32x4 bb1 = {b2r1, b2r1, b2r1, b2r1};                           \
        _Pragma("unroll")                                                     \
        for (int mt = 0; mt < 4; ++mt) {                                      \
            int rwb = wm * 64 + mt * 16 + quad * 4;                           \
            EPI4(OH2, acc[mt][0], bb0, rwb, wn * 32 + l15);                   \
            EPI4(OH2, acc[mt][1], bb1, rwb, wn * 32 + 16 + l15);              \
        }                                                                     \
    }                                                                         \
    BAR();   /* h2 visible; all h1 (slot 0..3) reads drained */               \
    /* tail: layer3 (reads slots 4..7) || next-ray prologue (slots 0..3) */   \
    const float4 w4 = *(const float4*)((const float*)(ws + OWGT)              \
                      + (r0 + (RI)) * NS + wave * 16 + quad * 4);             \
    f32x4 acc3 = vzero;                                                       \
    _Pragma("unroll")                                                         \
    for (int ks = 0; ks < 4; ++ks) {                                          \
        bf16x8 w3f = *(const bf16x8*)(w3r + (ks * 64 + lane) * 8);            \
        int c = ((ks * 8 + wave) * 64 + lane) ^ quad;                         \
        bf16x8 a3 = *(const bf16x8*)(pool + OH2 + c * 8);                     \
        acc3 = MF(a3, w3f, acc3);                                             \
    }                                                                         \
    if (PREF) {                                                               \
        LOADB2(bP0, bP1, 0);                  /* next-ray B reload (L1-hot) */\
        LOADB2(bQ0, bQ1, 1);                                                  \
        build_x(pool +        (cl >> 1) * 4096 + bxoff, pv_a);                \
        build_x(pool + 8192 + (cl >> 1) * 4096 + bxoff, pv_b);                \
        pv_a = pv_c; pv_b = pv_d;                                             \
        pv_c = ldch(ap, vp, 16 + cl);         /* g4 */                        \
        pv_d = ldch(ap, vp, 20 + cl);         /* g5 */                        \
    }                                                                         \
    float v = 0.f;                                                            \
    if (l15 < 3) {                                                            \
        v  = w4.x / (1.f + expf(-(acc3[0] + b3v)));                           \
        v += w4.y / (1.f + expf(-(acc3[1] + b3v)));                           \
        v += w4.z / (1.f + expf(-(acc3[2] + b3v)));                           \
        v += w4.w / (1.f + expf(-(acc3[3] + b3v)));                           \
    }                                                                         \
    v += __shfl_xor(v, 16);                                                   \
    v += __shfl_xor(v, 32);                                                   \
    if (lane < 3)                                                             \
        atomicAdd(&out_g[(r0 + (RI)) * 3 + lane], v);                         \
  }

// 8 waves: wave (wm = wave>>2, wn = wave&3) owns a 64x32 output tile
// (A-amp 4 via LDS, B-amp 2 via L1/L2 registers). 6 lgkm-only barriers per
// ray; 2 rays per block, straight-line (no loop back-edge -> no spill).
__global__ __launch_bounds__(512, 4) void render_kernel(
    const float* __restrict__ app_g,   const float* __restrict__ view_g,
    const float* __restrict__ b1_g,    const float* __restrict__ b2_g,
    const float* __restrict__ b3_g,    const u16* __restrict__ ws,
    float* __restrict__ out_g)
{
    __shared__ __align__(16) u16 pool[POOLSZ];

    const int tid  = threadIdx.x;
    const int lane = tid & 63;
    const int wave = tid >> 6;       // 0..7
    const int l15  = lane & 15;
    const int quad = lane >> 4;
    const int wm   = wave >> 2;      // row half (64 rows)
    const int wn   = wave & 3;       // col quarter (32 cols)

    const int r0  = blockIdx.x * RPB;
    const int rowl = tid & 127;      // X-build row (all 512 threads build)
    const int cl   = tid >> 7;       // X-build channel-local 0..3 (2 slices)
    const float* ap = app_g  + (r0 * NS + rowl) * 27;
    const float* vp = view_g + (r0 * NS + rowl) * 3;
    // hoisted per-thread build offset within a slice
    const int bxoff = (rowl >> 4) * 512 + (((cl & 1) * 32) + (rowl & 15)) * 8;

    // issue B loads for slices 0,1 ASAP (3-pair rotation P,Q,R)
    const u16* wp0 = ws + (wn * 128 + lane) * 8;
    bf16x8 bP0, bP1, bQ0, bQ1, bR0, bR1;
    LOADB2(bP0, bP1, 0);
    LOADB2(bQ0, bQ1, 1);

    // rolling input prefetch (4 resident: groups g..g+3's channel values)
    float pv_a = ldch(ap, vp, cl);           // g0
    float pv_b = ldch(ap, vp, 4 + cl);       // g1
    float pv_c = ldch(ap, vp, 8 + cl);       // g2
    float pv_d = ldch(ap, vp, 12 + cl);      // g3

    // ---- ray-0 prologue: build X groups 0,1 (slices 0..3) into slots 0,1 ----
    build_x(pool +        (cl >> 1) * 4096 + bxoff, pv_a);
    build_x(pool + 8192 + (cl >> 1) * 4096 + bxoff, pv_b);
    pv_a = pv_c; pv_b = pv_d;
    pv_c = ldch(ap, vp, 16 + cl);            // g4
    pv_d = ldch(ap, vp, 20 + cl);            // g5
    BAR();

    const f32x4 vzero = {0.f, 0.f, 0.f, 0.f};
    const u16* w3r = ws + 77824;
    const float b3v = (l15 < 3) ? b3_g[l15] : 0.f;
    f32x4 acc[4][2];

    RAY(0, 1);   // ray 0; interleaves ray-1 prologue under its tail
    BAR();       // ray boundary == ray-1's prologue barrier
    RAY(1, 0);   // ray 1
}

extern "C" void kernel_launch(void* const* d_in, const int* in_sizes, int n_in,
                              void* d_out, int out_size, void* d_ws, size_t ws_size,
                              hipStream_t stream) {
    (void)in_sizes; (void)n_in; (void)out_size; (void)ws_size;
    const float* sigma = (const float*)d_in[0];
    const float* app   = (const float*)d_in[1];
    const float* view  = (const float*)d_in[2];
    const float* dists = (const float*)d_in[3];
    const float* W1    = (const float*)d_in[4];
    const float* b1    = (const float*)d_in[5];
    const float* W2    = (const float*)d_in[6];
    const float* b2    = (const float*)d_in[7];
    const float* W3    = (const float*)d_in[8];
    const float* b3    = (const float*)d_in[9];
    float* out = (float*)d_out;

    u16* ws = (u16*)d_ws;   // 159744 B frag tables + 2 MB fp32 weights @ OWGT

    prep_kernel<<<1024, 256, 0, stream>>>(W1, W2, W3, sigma, dists, ws, out);
    render_kernel<<<NBLOCKS, 512, 0, stream>>>(app, view, b1, b2, b3, ws, out);
}

// Round 15
// 191.855 us; speedup vs baseline: 1.9570x; 1.2247x over previous
//
#include <hip/hip_runtime.h>
#include <math.h>

typedef unsigned short u16;
using bf16x8 = __attribute__((ext_vector_type(8))) short;
using f32x4  = __attribute__((ext_vector_type(4))) float;

#define NS      128
#define NBLOCKS 4096    // 1 ray per block, 512 threads (8 waves)
#define NSLICE  19      // 15 (W1) + 4 (W2) unified W slices of 4096 u16
#define OWGT    81920   // u16 offset of fp32 weight table (4096x128 f32, 2 MB)

// LDS pool (u16): X QUAD-buffer = 4 group slots x 8192 u16 = 64 KB.
// Slice s lives at (s&7)*4096. h1 overlays slots 0,1 (u16 0..16384);
// h2 overlays slots 2,3 (16384..32768) -> epilogue writes never race live
// readers, so no read-drain barriers. 6 barriers/ray total.
#define POOLSZ 32768
#define OH2    16384

// Raw barrier: drain LDS only; global register-prefetches stay in flight.
#define BAR() do { asm volatile("s_waitcnt lgkmcnt(0)" ::: "memory");        \
                   __builtin_amdgcn_s_barrier();                              \
                   asm volatile("" ::: "memory"); } while (0)

#define MF(A,B,C) __builtin_amdgcn_mfma_f32_16x16x32_bf16((A),(B),(C),0,0,0)

__device__ __forceinline__ u16 f2bf(float f) {           // host-prep path only
    unsigned int i = __float_as_uint(f);
    return (u16)((i + 0x7FFFu + ((i >> 16) & 1u)) >> 16);  // RNE
}

// pack two floats to bf16 pair [hi:lo] in one dword (single VALU op, RNE)
__device__ __forceinline__ unsigned pk(float hi, float lo) {
    unsigned r;
    asm("v_cvt_pk_bf16_f32 %0, %1, %2" : "=v"(r) : "v"(lo), "v"(hi));
    return r;
}

// Swizzled A-frag-order offset for a h [128x128] region: XOR (k>>3)&3 into
// the chunk index (readers apply chunk^quad) to spread the epilogue's
// column-wise u16 writes across more banks.
__device__ __forceinline__ int afoff_h(int m, int k) {
    int chunk = ((k >> 5) * 8 + (m >> 4)) * 64 + ((k >> 3) & 3) * 16 + (m & 15);
    chunk ^= (k >> 3) & 3;
    return chunk * 8 + (k & 7);
}

// channel/slot -> original mlp_in k index (reference ordering)
__device__ __forceinline__ int orig_k(int ch, int slot) {
    if (ch < 27) {
        if (slot == 0) return ch;
        if (slot <= 6) return 30 + ch * 6 + (slot - 1);     // sin(app)
        return 192 + ch * 6 + (slot - 7);                    // cos(app)
    } else {
        int c = ch - 27;
        if (slot == 0) return 27 + c;
        if (slot <= 6) return 354 + c * 6 + (slot - 1);      // sin(view)
        return 372 + c * 6 + (slot - 7);                     // cos(view)
    }
}

__device__ __forceinline__ float ldch(const float* ap, const float* vp, int c) {
    return (c < 27) ? ap[c] : vp[c - 27];
}

// build one channel-half of a frag-order X slice at a precomputed dst:
// slots [v, sin f0..5, cos f0..5, 0 x3] as two 16B chunks (dst, dst+128).
__device__ __forceinline__ void build_x(u16* dst, float v) {
    float rev = v * 0.15915494309189535f;
    rev -= floorf(rev);
    float s0 = __builtin_amdgcn_sinf(rev);
    float c0 = __builtin_amdgcn_cosf(rev);
    float s1 = 2.f * s0 * c0, c1 = c0 * c0 - s0 * s0;
    float s2 = 2.f * s1 * c1, c2 = c1 * c1 - s1 * s1;
    float s3 = 2.f * s2 * c2, c3 = c2 * c2 - s2 * s2;
    float s4 = 2.f * s3 * c3, c4 = c3 * c3 - s3 * s3;
    float s5 = 2.f * s4 * c4, c5 = c4 * c4 - s4 * s4;
    uint4 lo, hi;
    lo.x = pk(s0, v);  lo.y = pk(s2, s1);  lo.z = pk(s4, s3);  lo.w = pk(c0, s5);
    hi.x = pk(c2, c1); hi.y = pk(c4, c3);  hi.z = pk(0.f, c5); hi.w = 0u;
    *(uint4*)(dst)       = lo;
    *(uint4*)(dst + 128) = hi;
}

// W1 -> 15 slices, W2 -> 4 slices, W3 -> 4 mini B-frag slices (N padded 16);
// zeroes the output; computes per-ray transmittance weights (one wave/ray,
// identical shuffle-scan math to the in-render scan -> bit-exact).
__global__ __launch_bounds__(256) void prep_kernel(
    const float* __restrict__ W1, const float* __restrict__ W2,
    const float* __restrict__ W3, const float* __restrict__ sigma_g,
    const float* __restrict__ dists_g, u16* __restrict__ ws,
    float* __restrict__ out)
{
    int idx = blockIdx.x * 256 + threadIdx.x;
    if (idx < 12288) out[idx] = 0.f;                 // 4096 rays x 3
    if (idx < 61440) {                               // W1r: [ks15][nt8][lane64][j8]
        int j = idx & 7, lane = (idx >> 3) & 63, nt = (idx >> 9) & 7, ks = idx >> 12;
        int q = lane >> 4, l15 = lane & 15;
        int klocal = q * 8 + j;                      // 0..31
        int ch = ks * 2 + (klocal >> 4);
        int slot = klocal & 15;
        int n = nt * 16 + l15;
        ws[idx] = (slot < 13) ? f2bf(W1[orig_k(ch, slot) * 128 + n]) : (u16)0;
    } else if (idx < 77824) {                        // W2r: [ks4][nt8][lane64][j8]
        int i2 = idx - 61440;
        int j = i2 & 7, lane = (i2 >> 3) & 63, nt = (i2 >> 9) & 7, ks = i2 >> 12;
        int k = ks * 32 + (lane >> 4) * 8 + j;
        int n = nt * 16 + (lane & 15);
        ws[idx] = f2bf(W2[k * 128 + n]);
    } else if (idx < 79872) {                        // W3r: [ks4][lane64][j8], N pad 16
        int i3 = idx - 77824;
        int j = i3 & 7, lane = (i3 >> 3) & 63, ks = i3 >> 9;
        int k = ks * 32 + (lane >> 4) * 8 + j;
        int n = lane & 15;
        ws[idx] = (n < 3) ? f2bf(W3[k * 3 + n]) : (u16)0;
    }
    // ---- weights: wave (idx>>6) owns ray (idx>>6); lane ln handles samples
    // ln and ln+64 (same op sequence as the old two-wave render scan). ----
    {
        int ray = idx >> 6, ln = idx & 63;           // 1024 blocks x 4 waves = 4096
        float* wgt = (float*)(ws + OWGT);
        int base = ray * NS;
        float x0 = sigma_g[base + ln] - 10.f;
        float sp0 = (x0 > 20.f) ? x0 : log1pf(expf(x0));
        float a0 = 1.f - expf(-sp0 * dists_g[base + ln] * 25.f);
        float x1 = sigma_g[base + 64 + ln] - 10.f;
        float sp1 = (x1 > 20.f) ? x1 : log1pf(expf(x1));
        float a1 = 1.f - expf(-sp1 * dists_g[base + 64 + ln] * 25.f);
        if (ln == 63) a1 = 1.f;                      // last sample forced opaque
        float p0 = 1.f - a0 + 1e-10f;
        float p1 = 1.f - a1 + 1e-10f;
        #pragma unroll
        for (int d = 1; d < 64; d <<= 1) {
            float v0 = __shfl_up(p0, d);
            float v1 = __shfl_up(p1, d);
            if (ln >= d) { p0 *= v0; p1 *= v1; }
        }
        float S0 = __shfl(p0, 63);                   // first-half total
        float q0 = __shfl_up(p0, 1);
        float q1 = __shfl_up(p1, 1);
        wgt[base + ln]      = a0 * ((ln == 0) ? 1.f : q0);
        wgt[base + 64 + ln] = a1 * ((ln == 0) ? 1.f : q1) * S0;
    }
}

// Load one slice's 2 B-frags (wave's 32-col strip) into named registers.
#define LOADB2(N0, N1, s)                                                     \
    if ((s) < NSLICE) {                                                       \
        const u16* wp = wp0 + (s) * 4096;                                     \
        N0 = *(const bf16x8*)(wp);                                            \
        N1 = *(const bf16x8*)(wp + 512);                                      \
    }

// One X-sourced K-slice: 4 A ds_reads (64-row strip, split 2+2) + 8 MFMA.
// Loads slice s+2's B-frags (3-pair rotation P,Q,R).
#define BODYX(s, C0,C1, N0,N1)                                                \
  {                                                                           \
    LOADB2(N0, N1, (s)+2);                                                    \
    const u16* ab = pool + ((s)&7)*4096 + (wm*256 + lane)*8;                  \
    bf16x8 a0 = *(const bf16x8*)(ab);                                         \
    bf16x8 a1 = *(const bf16x8*)(ab + 512);                                   \
    __builtin_amdgcn_s_setprio(1);                                            \
    acc[0][0]=MF(a0,C0,acc[0][0]); acc[0][1]=MF(a0,C1,acc[0][1]);             \
    acc[1][0]=MF(a1,C0,acc[1][0]); acc[1][1]=MF(a1,C1,acc[1][1]);             \
    a0 = *(const bf16x8*)(ab + 1024);                                         \
    a1 = *(const bf16x8*)(ab + 1536);                                         \
    acc[2][0]=MF(a0,C0,acc[2][0]); acc[2][1]=MF(a0,C1,acc[2][1]);             \
    acc[3][0]=MF(a1,C0,acc[3][0]); acc[3][1]=MF(a1,C1,acc[3][1]);             \
    __builtin_amdgcn_s_setprio(0);                                            \
  }

// First slice: C-in = 0 folded into the MFMA (no acc zero-init pass).
#define BODYX0(s, C0,C1, N0,N1)                                               \
  {                                                                           \
    LOADB2(N0, N1, (s)+2);                                                    \
    const u16* ab = pool + ((s)&7)*4096 + (wm*256 + lane)*8;                  \
    bf16x8 a0 = *(const bf16x8*)(ab);                                         \
    bf16x8 a1 = *(const bf16x8*)(ab + 512);                                   \
    __builtin_amdgcn_s_setprio(1);                                            \
    acc[0][0]=MF(a0,C0,vzero); acc[0][1]=MF(a0,C1,vzero);                     \
    acc[1][0]=MF(a1,C0,vzero); acc[1][1]=MF(a1,C1,vzero);                     \
    a0 = *(const bf16x8*)(ab + 1024);                                         \
    a1 = *(const bf16x8*)(ab + 1536);                                         \
    acc[2][0]=MF(a0,C0,vzero); acc[2][1]=MF(a0,C1,vzero);                     \
    acc[3][0]=MF(a1,C0,vzero); acc[3][1]=MF(a1,C1,vzero);                     \
    __builtin_amdgcn_s_setprio(0);                                            \
  }

// One h-sourced K-slice (GEMM2): A from swizzled h1 chunks (slots 0,1).
#define BODYH(s, C0,C1, N0,N1)                                                \
  {                                                                           \
    LOADB2(N0, N1, (s)+2);                                                    \
    int cb = ((((s)-15)*512) + wm*256 + lane) ^ quad;                         \
    bf16x8 a0 = *(const bf16x8*)(pool + cb*8);                                \
    bf16x8 a1 = *(const bf16x8*)(pool + (cb+64)*8);                           \
    __builtin_amdgcn_s_setprio(1);                                            \
    acc[0][0]=MF(a0,C0,acc[0][0]); acc[0][1]=MF(a0,C1,acc[0][1]);             \
    acc[1][0]=MF(a1,C0,acc[1][0]); acc[1][1]=MF(a1,C1,acc[1][1]);             \
    a0 = *(const bf16x8*)(pool + (cb+128)*8);                                 \
    a1 = *(const bf16x8*)(pool + (cb+192)*8);                                 \
    acc[2][0]=MF(a0,C0,acc[2][0]); acc[2][1]=MF(a0,C1,acc[2][1]);             \
    acc[3][0]=MF(a1,C0,acc[3][0]); acc[3][1]=MF(a1,C1,acc[3][1]);             \
    __builtin_amdgcn_s_setprio(0);                                            \
  }

// First GEMM2 slice: C-in = 0 folded in (no acc reset pass after epilogue 1).
#define BODYH0(s, C0,C1, N0,N1)                                               \
  {                                                                           \
    LOADB2(N0, N1, (s)+2);                                                    \
    int cb = ((((s)-15)*512) + wm*256 + lane) ^ quad;                         \
    bf16x8 a0 = *(const bf16x8*)(pool + cb*8);                                \
    bf16x8 a1 = *(const bf16x8*)(pool + (cb+64)*8);                           \
    __builtin_amdgcn_s_setprio(1);                                            \
    acc[0][0]=MF(a0,C0,vzero); acc[0][1]=MF(a0,C1,vzero);                     \
    acc[1][0]=MF(a1,C0,vzero); acc[1][1]=MF(a1,C1,vzero);                     \
    a0 = *(const bf16x8*)(pool + (cb+128)*8);                                 \
    a1 = *(const bf16x8*)(pool + (cb+192)*8);                                 \
    acc[2][0]=MF(a0,C0,vzero); acc[2][1]=MF(a0,C1,vzero);                     \
    acc[3][0]=MF(a1,C0,vzero); acc[3][1]=MF(a1,C1,vzero);                     \
    __builtin_amdgcn_s_setprio(0);                                            \
  }

// End of 2-group phase p: build groups 2p+2, 2p+3 into their slots, roll the
// 4-deep input prefetch (load groups 2p+6, 2p+7), single barrier.
#define GENDQ(p)                                                              \
  {                                                                           \
    if (8*(p)+8  + cl < 30)                                                   \
        build_x(pool + ((2*(p)+2)&3)*8192 + (cl>>1)*4096 + bxoff, pv_a);      \
    if (8*(p)+12 + cl < 30)                                                   \
        build_x(pool + ((2*(p)+3)&3)*8192 + (cl>>1)*4096 + bxoff, pv_b);      \
    pv_a = pv_c; pv_b = pv_d;                                                 \
    if (8*(p)+24 + cl < 30) pv_c = ldch(ap, vp, 8*(p)+24 + cl);               \
    if (8*(p)+28 + cl < 30) pv_d = ldch(ap, vp, 8*(p)+28 + cl);               \
    BAR();                                                                    \
  }

// Vectorized epilogue store: packed add/max + paired bf16 cvt, 4 u16 writes.
#define EPI4(OFS, ACC, BB, rwb, col)                                          \
  { f32x4 t_ = ACC + BB;                                                      \
    t_ = __builtin_elementwise_max(t_, vzero);                                \
    unsigned w01_ = pk(t_[1], t_[0]);                                         \
    unsigned w23_ = pk(t_[3], t_[2]);                                         \
    pool[(OFS) + afoff_h((rwb) + 0, col)] = (u16)w01_;                        \
    pool[(OFS) + afoff_h((rwb) + 1, col)] = (u16)(w01_ >> 16);                \
    pool[(OFS) + afoff_h((rwb) + 2, col)] = (u16)w23_;                        \
    pool[(OFS) + afoff_h((rwb) + 3, col)] = (u16)(w23_ >> 16); }

// 8 waves: wave (wm = wave>>2, wn = wave&3) owns a 64x32 output tile
// (A-amp 4 via LDS, B-amp 2 via L1/L2 registers). 6 lgkm-only barriers.
// Head: no scan (weights precomputed in prep); tail: direct weighted
// reduction with float4 weight loads, no part buffer, no final barrier.
// NOTE (r13/r14): multi-ray blocks -- looped OR straight-line -- spill
// (seam liveness exceeds the 128-reg (512,4) budget). 1 ray/block is final.
__global__ __launch_bounds__(512, 4) void render_kernel(
    const float* __restrict__ app_g,   const float* __restrict__ view_g,
    const float* __restrict__ b1_g,    const float* __restrict__ b2_g,
    const float* __restrict__ b3_g,    const u16* __restrict__ ws,
    float* __restrict__ out_g)
{
    __shared__ __align__(16) u16 pool[POOLSZ];

    const int tid  = threadIdx.x;
    const int lane = tid & 63;
    const int wave = tid >> 6;       // 0..7
    const int l15  = lane & 15;
    const int quad = lane >> 4;
    const int wm   = wave >> 2;      // row half (64 rows)
    const int wn   = wave & 3;       // col quarter (32 cols)

    const int r  = blockIdx.x;
    const int rb = r * NS;
    const int row = tid & 127;       // X-build row (all 512 threads build)
    const int cl  = tid >> 7;        // X-build channel-local 0..3 (2 slices)
    const float* ap = app_g  + (rb + row) * 27;
    const float* vp = view_g + (rb + row) * 3;
    // hoisted per-thread build offset within a slice
    const int bxoff = (row >> 4) * 512 + (((cl & 1) * 32) + (row & 15)) * 8;

    // issue B loads for slices 0,1 ASAP (3-pair rotation P,Q,R)
    const u16* wp0 = ws + (wn * 128 + lane) * 8;
    bf16x8 bP0, bP1, bQ0, bQ1, bR0, bR1;
    LOADB2(bP0, bP1, 0);
    LOADB2(bQ0, bQ1, 1);

    // rolling input prefetch (4 resident: groups g..g+3's channel values)
    float pv_a = ldch(ap, vp, cl);           // g0
    float pv_b = ldch(ap, vp, 4 + cl);       // g1
    float pv_c = ldch(ap, vp, 8 + cl);       // g2
    float pv_d = ldch(ap, vp, 12 + cl);      // g3

    // ---- pre-build X groups 0,1 (slices 0..3) into slots 0,1 ----
    build_x(pool +        (cl >> 1) * 4096 + bxoff, pv_a);
    build_x(pool + 8192 + (cl >> 1) * 4096 + bxoff, pv_b);
    pv_a = pv_c; pv_b = pv_d;
    pv_c = ldch(ap, vp, 16 + cl);            // g4
    pv_d = ldch(ap, vp, 20 + cl);            // g5
    BAR();

    const f32x4 vzero = {0.f, 0.f, 0.f, 0.f};
    f32x4 acc[4][2];

    // ---- GEMM1: slices 0..14, 4-slice phases (pair s%3: 0=P 1=Q 2=R) ----
    BODYX0(0, bP0,bP1, bR0,bR1);              // C=0 folded: no acc init pass
    BODYX(1,  bQ0,bQ1, bP0,bP1);
    BODYX(2,  bR0,bR1, bQ0,bQ1);
    BODYX(3,  bP0,bP1, bR0,bR1);  GENDQ(0);   // builds g2,g3 (slices 4..7)
    BODYX(4,  bQ0,bQ1, bP0,bP1);
    BODYX(5,  bR0,bR1, bQ0,bQ1);
    BODYX(6,  bP0,bP1, bR0,bR1);
    BODYX(7,  bQ0,bQ1, bP0,bP1);  GENDQ(1);   // builds g4,g5 (slices 8..11)
    BODYX(8,  bR0,bR1, bQ0,bQ1);
    BODYX(9,  bP0,bP1, bR0,bR1);
    BODYX(10, bQ0,bQ1, bP0,bP1);
    BODYX(11, bR0,bR1, bQ0,bQ1);  GENDQ(2);   // builds g6,g7 (slices 12..14)
    // b1 issued here so its latency hides under the last GEMM1 phase
    const float b1r0 = b1_g[wn * 32 + l15];
    const float b1r1 = b1_g[wn * 32 + 16 + l15];
    BODYX(12, bP0,bP1, bR0,bR1);
    BODYX(13, bQ0,bQ1, bP0,bP1);              // loads slice 15 -> P
    BODYX(14, bR0,bR1, bQ0,bQ1);              // loads slice 16 -> Q

    // ---- epilogue 1 (NO pre-barrier): h1 -> slots 0,1; concurrent
    // slice-12..14 reads live in slots 2,3 (disjoint). ----
    {
        const f32x4 bb0 = {b1r0, b1r0, b1r0, b1r0};
        const f32x4 bb1 = {b1r1, b1r1, b1r1, b1r1};
        #pragma unroll
        for (int mt = 0; mt < 4; ++mt) {
            int rwb = wm * 64 + mt * 16 + quad * 4;
            EPI4(0, acc[mt][0], bb0, rwb, wn * 32 + l15);
            EPI4(0, acc[mt][1], bb1, rwb, wn * 32 + 16 + l15);
        }
    }
    BAR();   // h1 visible to all waves AND slot-2,3 reads drained

    const float b2r0 = b2_g[wn * 32 + l15];
    const float b2r1 = b2_g[wn * 32 + 16 + l15];

    // ---- GEMM2: slices 15..18 (h1 @ W2), barrier-free run ----
    BODYH0(15, bP0,bP1, bR0,bR1);             // C=0 folded; loads 17 -> R
    BODYH(16, bQ0,bQ1, bP0,bP1);              // loads slice 18 -> P
    BODYH(17, bR0,bR1, bQ0,bQ1);
    BODYH(18, bP0,bP1, bR0,bR1);

    // ---- epilogue 2 (NO pre-barrier): h2 -> slots 2,3; concurrent GEMM2
    // reads live in slots 0,1 (disjoint); old slot-2,3 readers drained. ----
    {
        const f32x4 bb0 = {b2r0, b2r0, b2r0, b2r0};
        const f32x4 bb1 = {b2r1, b2r1, b2r1, b2r1};
        #pragma unroll
        for (int mt = 0; mt < 4; ++mt) {
            int rwb = wm * 64 + mt * 16 + quad * 4;
            EPI4(OH2, acc[mt][0], bb0, rwb, wn * 32 + l15);
            EPI4(OH2, acc[mt][1], bb1, rwb, wn * 32 + 16 + l15);
        }
    }
    BAR();   // h2 visible

    // ---- layer 3 via MFMA + direct weighted reduction (no part, no BAR) ----
    const u16* w3r = ws + 77824;
    // issue the weight load first so it flies under the MFMAs
    const float4 w4 = *(const float4*)((const float*)(ws + OWGT)
                                       + rb + wave * 16 + quad * 4);
    const float b3v = (l15 < 3) ? b3_g[l15] : 0.f;
    f32x4 acc3 = vzero;
    #pragma unroll
    for (int ks = 0; ks < 4; ++ks) {
        bf16x8 w3f = *(const bf16x8*)(w3r + (ks * 64 + lane) * 8);
        int c = ((ks * 8 + wave) * 64 + lane) ^ quad;
        bf16x8 a3 = *(const bf16x8*)(pool + OH2 + c * 8);
        acc3 = MF(a3, w3f, acc3);
    }
    float v = 0.f;
    if (l15 < 3) {
        v  = w4.x / (1.f + expf(-(acc3[0] + b3v)));
        v += w4.y / (1.f + expf(-(acc3[1] + b3v)));
        v += w4.z / (1.f + expf(-(acc3[2] + b3v)));
        v += w4.w / (1.f + expf(-(acc3[3] + b3v)));
    }
    v += __shfl_xor(v, 16);      // sum the 4 quads (rows) of this wave
    v += __shfl_xor(v, 32);
    if (lane < 3)                // out zeroed by prep; 8 wave-partials/color
        atomicAdd(&out_g[r * 3 + lane], v);
}

extern "C" void kernel_launch(void* const* d_in, const int* in_sizes, int n_in,
                              void* d_out, int out_size, void* d_ws, size_t ws_size,
                              hipStream_t stream) {
    (void)in_sizes; (void)n_in; (void)out_size; (void)ws_size;
    const float* sigma = (const float*)d_in[0];
    const float* app   = (const float*)d_in[1];
    const float* view  = (const float*)d_in[2];
    const float* dists = (const float*)d_in[3];
    const float* W1    = (const float*)d_in[4];
    const float* b1    = (const float*)d_in[5];
    const float* W2    = (const float*)d_in[6];
    const float* b2    = (const float*)d_in[7];
    const float* W3    = (const float*)d_in[8];
    const float* b3    = (const float*)d_in[9];
    float* out = (float*)d_out;

    u16* ws = (u16*)d_ws;   // 159744 B frag tables + 2 MB fp32 weights @ OWGT

    prep_kernel<<<1024, 256, 0, stream>>>(W1, W2, W3, sigma, dists, ws, out);
    render_kernel<<<NBLOCKS, 512, 0, stream>>>(app, view, b1, b2, b3, ws, out);
}